// Round 1
// baseline (77.494 us; speedup 1.0000x reference)
//
#include <hip/hip_runtime.h>
#include <hip/hip_bf16.h>
#include <math.h>

typedef __attribute__((ext_vector_type(8))) short bf16x8;
typedef __attribute__((ext_vector_type(4))) float f32x4;
typedef unsigned short ushort_t;

#define NP 14400   // patches per video
#define KP 96      // padded feature dim
#define KD 75      // real feature dim
#define NRB 150    // row blocks of 96 rows
#define NS 6       // column segments
#define SEG 2400   // cols per segment
#define NIT 25     // 2400 / 96 iters per block

__device__ __forceinline__ ushort_t f2bf(float f) {
  unsigned u = __float_as_uint(f);
  u += 0x7FFF + ((u >> 16) & 1);   // RNE
  return (ushort_t)(u >> 16);
}
__device__ __forceinline__ float bf2f(ushort_t b) {
  return __uint_as_float(((unsigned)b) << 16);
}

// ---------------- prep: extract (1,5,5) patches -> bf16 (+ norms) ---------
// Q stores -2 * bf16(q) (exact x2 scaling); K stores bf16(k).
// qn/kn are fp32 norms of the bf16-rounded values (consistent math).
__global__ __launch_bounds__(256) void prep_kernel(
    const float* __restrict__ resv, const float* __restrict__ valv,
    ushort_t* __restrict__ Qb, ushort_t* __restrict__ Kb,
    float* __restrict__ qn, float* __restrict__ kn) {
  int w = threadIdx.x >> 6;
  int lane = threadIdx.x & 63;
  int pg = blockIdx.x * 4 + w;          // 0..28799
  int isK = pg >= NP;
  int p = isK ? pg - NP : pg;
  const float* src = isK ? valv : resv;
  int t = p / 3600; int rem = p - t * 3600;
  int y = rem / 60;  int x = rem - y * 60;

  float v0 = 0.f, v1 = 0.f;
  {
    int d = lane;
    if (d < KD) {
      int c = d / 25; int r = d - c * 25; int dy = r / 5; int dx = r - dy * 5;
      v0 = src[((c * 4 + t) * 64 + (y + dy)) * 64 + (x + dx)];
    }
  }
  {
    int d = lane + 64;
    if (d < KD) {
      int c = d / 25; int r = d - c * 25; int dy = r / 5; int dx = r - dy * 5;
      v1 = src[((c * 4 + t) * 64 + (y + dy)) * 64 + (x + dx)];
    }
  }
  ushort_t b0 = f2bf(v0), b1 = f2bf(v1);
  float f0 = bf2f(b0), f1 = bf2f(b1);
  ushort_t* dst = isK ? Kb : Qb;
  ushort_t s0 = isK ? b0 : f2bf(-2.f * f0);
  ushort_t s1 = isK ? b1 : f2bf(-2.f * f1);
  dst[(size_t)p * KP + lane] = s0;
  if (lane + 64 < KP) dst[(size_t)p * KP + lane + 64] = s1;

  float sq = f0 * f0 + f1 * f1;
  #pragma unroll
  for (int off = 32; off; off >>= 1) sq += __shfl_down(sq, off, 64);
  if (lane == 0) (isK ? kn : qn)[p] = sq;
}

// ---------------- main: per-row min over (kn - 2 q.k) via MFMA ------------
__global__ __launch_bounds__(256, 2) void knn_kernel(
    const ushort_t* __restrict__ Qb, const ushort_t* __restrict__ Kb,
    const float* __restrict__ kn, float* __restrict__ rminw) {
  int bid = blockIdx.x;                 // 0..899
  int rowblk = bid / NS;
  int ns = bid - rowblk * NS;
  int brow = rowblk * 96;
  int nsbase = ns * SEG;
  int lane = threadIdx.x & 63;
  int w = threadIdx.x >> 6;
  int wr = w >> 1, wq = w & 1;          // 2x2 wave tiling
  int l15 = lane & 15, l4 = lane >> 4;

  // A fragments: loop-invariant, kept in registers. Row = l&15, kchunk = l>>4.
  const ushort_t* Abase = Qb + (size_t)(brow + wr * 48 + l15) * KP + l4 * 8;
  bf16x8 af[3][3];
  #pragma unroll
  for (int rt = 0; rt < 3; ++rt)
    #pragma unroll
    for (int ks = 0; ks < 3; ++ks)
      af[rt][ks] = *(const bf16x8*)(Abase + rt * 16 * KP + ks * 32);

  float rmin[3][4];
  #pragma unroll
  for (int rt = 0; rt < 3; ++rt)
    #pragma unroll
    for (int j = 0; j < 4; ++j) rmin[rt][j] = INFINITY;

  bf16x8 bA[3][3], bB[3][3];
  float kA[3], kB[3];

  auto loadB = [&](bf16x8 (&bf)[3][3], float (&kv)[3], int itv) {
    int c0 = nsbase + itv * 96 + wq * 48;
    const ushort_t* Bbase = Kb + (size_t)(c0 + l15) * KP + l4 * 8;
    #pragma unroll
    for (int ct = 0; ct < 3; ++ct) {
      #pragma unroll
      for (int ks = 0; ks < 3; ++ks)
        bf[ct][ks] = *(const bf16x8*)(Bbase + ct * 16 * KP + ks * 32);
      kv[ct] = kn[c0 + ct * 16 + l15];
    }
  };

  auto comp = [&](const bf16x8 (&bf)[3][3], const float (&kv)[3]) {
    f32x4 acc[3][3];
    // init with kn[col]: after 3 MFMAs acc = kn - 2*q.k  (A holds -2q)
    #pragma unroll
    for (int rt = 0; rt < 3; ++rt)
      #pragma unroll
      for (int ct = 0; ct < 3; ++ct)
        acc[rt][ct] = (f32x4){kv[ct], kv[ct], kv[ct], kv[ct]};
    #pragma unroll
    for (int ks = 0; ks < 3; ++ks)
      #pragma unroll
      for (int ct = 0; ct < 3; ++ct)
        #pragma unroll
        for (int rt = 0; rt < 3; ++rt)
          acc[rt][ct] = __builtin_amdgcn_mfma_f32_16x16x32_bf16(
              af[rt][ks], bf[ct][ks], acc[rt][ct], 0, 0, 0);
    #pragma unroll
    for (int rt = 0; rt < 3; ++rt)
      #pragma unroll
      for (int j = 0; j < 4; ++j) {
        float m = rmin[rt][j];
        #pragma unroll
        for (int ct = 0; ct < 3; ++ct) m = fminf(m, acc[rt][ct][j]);
        rmin[rt][j] = m;
      }
  };

  // register-double-buffered sweep over this block's key segment
  loadB(bA, kA, 0);
  for (int it = 0; it < NIT; it += 2) {
    if (it + 1 < NIT) loadB(bB, kB, it + 1);
    comp(bA, kA);
    if (it + 1 < NIT) {
      if (it + 2 < NIT) loadB(bA, kA, it + 2);
      comp(bB, kB);
    }
  }

  // cross-lane min within each 16-lane col group (C/D: col=l&15, row=(l>>4)*4+j)
  __shared__ float sred[4][48];
  #pragma unroll
  for (int rt = 0; rt < 3; ++rt)
    #pragma unroll
    for (int j = 0; j < 4; ++j) {
      float m = rmin[rt][j];
      m = fminf(m, __shfl_xor(m, 1, 64));
      m = fminf(m, __shfl_xor(m, 2, 64));
      m = fminf(m, __shfl_xor(m, 4, 64));
      m = fminf(m, __shfl_xor(m, 8, 64));
      if (l15 == 0) sred[w][rt * 16 + l4 * 4 + j] = m;
    }
  __syncthreads();
  int tt = threadIdx.x;
  if (tt < 96) {
    int h = tt / 48, r = tt - (tt / 48) * 48;
    float m = fminf(sred[h * 2][r], sred[h * 2 + 1][r]);  // combine col-halves
    rminw[(size_t)ns * NP + brow + h * 48 + r] = m;
  }
}

// ---------------- reduce: min over segments + qn, partial sums ------------
__global__ __launch_bounds__(64) void rowmin_kernel(
    const float* __restrict__ rminw, const float* __restrict__ qn,
    float* __restrict__ partial) {
  int r = blockIdx.x * 64 + threadIdx.x;   // grid 225 -> covers 14400
  float m = INFINITY;
  #pragma unroll
  for (int s = 0; s < NS; ++s) m = fminf(m, rminw[(size_t)s * NP + r]);
  float val = m + qn[r];
  #pragma unroll
  for (int off = 32; off; off >>= 1) val += __shfl_down(val, off, 64);
  if (threadIdx.x == 0) partial[blockIdx.x] = val;
}

__global__ __launch_bounds__(256) void final_kernel(
    const float* __restrict__ partial, float* __restrict__ out) {
  int t = threadIdx.x;
  float v = (t < 225) ? partial[t] : 0.f;
  #pragma unroll
  for (int off = 32; off; off >>= 1) v += __shfl_down(v, off, 64);
  __shared__ float s[4];
  if ((t & 63) == 0) s[t >> 6] = v;
  __syncthreads();
  if (t == 0) out[0] = s[0] + s[1] + s[2] + s[3];
}

extern "C" void kernel_launch(void* const* d_in, const int* in_sizes, int n_in,
                              void* d_out, int out_size, void* d_ws, size_t ws_size,
                              hipStream_t stream) {
  const float* resv = (const float*)d_in[0];
  const float* valv = (const float*)d_in[1];
  char* ws = (char*)d_ws;
  ushort_t* Qb   = (ushort_t*)ws;                 // 2,764,800 B
  ushort_t* Kb   = (ushort_t*)(ws + 2764800);     // 2,764,800 B
  float* qn      = (float*)(ws + 5529600);        //    57,600 B
  float* kn      = (float*)(ws + 5587200);        //    57,600 B
  float* rminw   = (float*)(ws + 5644800);        //   345,600 B
  float* partial = (float*)(ws + 5990400);        //       900 B
  float* out = (float*)d_out;

  prep_kernel<<<7200, 256, 0, stream>>>(resv, valv, Qb, Kb, qn, kn);
  knn_kernel<<<900, 256, 0, stream>>>(Qb, Kb, kn, rminw);
  rowmin_kernel<<<225, 64, 0, stream>>>(rminw, qn, partial);
  final_kernel<<<1, 256, 0, stream>>>(partial, out);
}

// Round 3
// 58.971 us; speedup vs baseline: 1.3141x; 1.3141x over previous
//
#include <hip/hip_runtime.h>
#include <hip/hip_bf16.h>
#include <math.h>

typedef __attribute__((ext_vector_type(8))) short bf16x8;
typedef __attribute__((ext_vector_type(4))) float f32x4;
typedef unsigned short ushort_t;

#define NP 14400   // patches per video
#define KP 96      // padded feature dim (75 real + kn in slots 75/76)
#define KD 75      // real feature dim
#define NS 6       // column segments
#define SEG 2400   // cols per segment
#define NIT 25     // 2400 / 96 iters per block
#define CPAD 104   // padded col stride in LDS (elems) = 208 B = 13 x 16B chunks

__device__ __forceinline__ ushort_t f2bf(float f) {
  unsigned u = __float_as_uint(f);
  u += 0x7FFF + ((u >> 16) & 1);   // RNE
  return (ushort_t)(u >> 16);
}
__device__ __forceinline__ float bf2f(ushort_t b) {
  return __uint_as_float(((unsigned)b) << 16);
}

// ---------------- prep: extract (1,5,5) patches -> bf16 ---------
// Q rows: slots 0..74 = bf16(-2*q), slots 75,76 = 1.0, rest 0. qn = fp32 norm.
// K rows: slots 0..74 = bf16(k), slot 75 = bf16(kn), 76 = bf16(kn residual), rest 0.
// => MFMA(A=-2q|1|1, B=k|kn_hi|kn_lo) = kn - 2 q.k directly.
__global__ __launch_bounds__(256) void prep_kernel(
    const float* __restrict__ resv, const float* __restrict__ valv,
    ushort_t* __restrict__ Qb, ushort_t* __restrict__ Kb,
    float* __restrict__ qn) {
  int w = threadIdx.x >> 6;
  int lane = threadIdx.x & 63;
  int pg = blockIdx.x * 4 + w;          // 0..28799
  int isK = pg >= NP;
  int p = isK ? pg - NP : pg;
  const float* src = isK ? valv : resv;
  int t = p / 3600; int rem = p - t * 3600;
  int y = rem / 60;  int x = rem - y * 60;

  float v0, v1 = 0.f;
  {
    int d = lane;  // always < 75
    int c = d / 25; int r = d - c * 25; int dy = r / 5; int dx = r - dy * 5;
    v0 = src[((c * 4 + t) * 64 + (y + dy)) * 64 + (x + dx)];
  }
  if (lane < 11) {
    int d = lane + 64;
    int c = d / 25; int r = d - c * 25; int dy = r / 5; int dx = r - dy * 5;
    v1 = src[((c * 4 + t) * 64 + (y + dy)) * 64 + (x + dx)];
  }
  ushort_t b0 = f2bf(v0), b1 = f2bf(v1);
  float f0 = bf2f(b0), f1 = bf2f(b1);

  float sq = f0 * f0 + f1 * f1;
  #pragma unroll
  for (int off = 1; off < 64; off <<= 1) sq += __shfl_xor(sq, off, 64);
  // all lanes now hold the full (rounded) patch norm

  ushort_t* dst = isK ? Kb : Qb;
  ushort_t s0, s1;
  if (isK) {
    s0 = b0;
    ushort_t khi = f2bf(sq);
    ushort_t klo = f2bf(sq - bf2f(khi));
    s1 = (lane < 11) ? b1 : (lane == 11 ? khi : (lane == 12 ? klo : (ushort_t)0));
  } else {
    s0 = f2bf(-2.f * f0);
    s1 = (lane < 11) ? f2bf(-2.f * f1)
                     : ((lane == 11 || lane == 12) ? (ushort_t)0x3F80 : (ushort_t)0);
    if (lane == 0) qn[p] = sq;
  }
  dst[(size_t)p * KP + lane] = s0;
  if (lane < 32) dst[(size_t)p * KP + 64 + lane] = s1;
}

// ---------------- main: per-row min over (kn - 2 q.k) via MFMA ------------
// Block: 96 query rows x one 2400-col key segment. 4 waves, 2x2 tiling.
// B tiles (96 cols x 96 k) staged to LDS via global_load_lds, double-buffered.
// LDS layout: col-major, col stride 208 B (pad chunk 13 of each col unused)
// achieved by pre-swizzling the per-lane GLOBAL source (LDS dest stays linear).
__global__ __launch_bounds__(256, 4) void knn_kernel(
    const ushort_t* __restrict__ Qb, const ushort_t* __restrict__ Kb,
    float* __restrict__ rminw) {
  __shared__ ushort_t Bs[2][9984];   // 2 x 19968 B
  __shared__ float sred[4][48];

  // XCD-bijective swizzle (m204): 900 blocks, 8 XCDs, ns-major linear order
  // -> each XCD reads only 1-2 key segments (L2-resident).
  int b = blockIdx.x;
  int xcd = b & 7, pos = b >> 3;
  int lin = (xcd < 4 ? xcd * 113 : 452 + (xcd - 4) * 112) + pos;
  int ns = lin / 150, rowblk = lin - ns * 150;
  int brow = rowblk * 96;
  int lane = threadIdx.x & 63;
  int w = threadIdx.x >> 6;
  int wr = w >> 1, wq = w & 1;
  int l15 = lane & 15, l4 = lane >> 4;

  // --- staging address precompute: 20 wave-issues of 1KB, 5 per wave ---
  const char* gseg = (const char*)Kb + (size_t)ns * SEG * 192;
  int goff[5]; int ldsoff[5]; bool cvalid[5];
  #pragma unroll
  for (int j = 0; j < 5; ++j) {
    int i = w + 4 * j;            // issue index 0..19
    int c = i * 64 + lane;        // padded 16B-chunk index, < 1280
    int col = c / 13;             // 13 chunks per padded col
    int off = c - col * 13;       // chunk within col; 12 == pad
    if (col > 95) col = 95;
    int boff = (off == 12) ? 0 : off * 16;
    goff[j] = col * 192 + boff;   // real data is 192 B per col
    ldsoff[j] = i * 1024;
    cvalid[j] = (c < 1248);       // 96 cols * 13 chunks
  }

  auto stage = [&](int buf, int it) {
    const char* g = gseg + it * 18432;
    char* lb = (char*)&Bs[buf][0];
    #pragma unroll
    for (int j = 0; j < 5; ++j) {
      if (cvalid[j])
        __builtin_amdgcn_global_load_lds(
            (const __attribute__((address_space(1))) void*)(g + goff[j]),
            (__attribute__((address_space(3))) void*)(lb + ldsoff[j]),
            16, 0, 0);
    }
  };

  stage(0, 0);

  // A fragments: loop-invariant registers. Row = l&15, kchunk = l>>4.
  const ushort_t* Abase = Qb + (size_t)(brow + wr * 48 + l15) * KP + l4 * 8;
  bf16x8 af[3][3];
  #pragma unroll
  for (int rt = 0; rt < 3; ++rt)
    #pragma unroll
    for (int ks = 0; ks < 3; ++ks)
      af[rt][ks] = *(const bf16x8*)(Abase + rt * 16 * KP + ks * 32);

  float rmin[3][4];
  #pragma unroll
  for (int rt = 0; rt < 3; ++rt)
    #pragma unroll
    for (int j = 0; j < 4; ++j) rmin[rt][j] = INFINITY;

  __syncthreads();   // drains vmcnt(0): buf0 staged & visible

  for (int it = 0; it < NIT; ++it) {
    int buf = it & 1;
    if (it + 1 < NIT) stage(buf ^ 1, it + 1);

    f32x4 acc[3][3];
    #pragma unroll
    for (int rt = 0; rt < 3; ++rt)
      #pragma unroll
      for (int ct = 0; ct < 3; ++ct)
        acc[rt][ct] = (f32x4){0.f, 0.f, 0.f, 0.f};

    #pragma unroll
    for (int ks = 0; ks < 3; ++ks) {
      bf16x8 bf[3];
      #pragma unroll
      for (int ct = 0; ct < 3; ++ct)
        bf[ct] = *(const bf16x8*)&Bs[buf][(wq * 48 + ct * 16 + l15) * CPAD +
                                          ks * 32 + l4 * 8];
      #pragma unroll
      for (int ct = 0; ct < 3; ++ct)
        #pragma unroll
        for (int rt = 0; rt < 3; ++rt)
          acc[rt][ct] = __builtin_amdgcn_mfma_f32_16x16x32_bf16(
              af[rt][ks], bf[ct], acc[rt][ct], 0, 0, 0);
    }

    #pragma unroll
    for (int rt = 0; rt < 3; ++rt)
      #pragma unroll
      for (int j = 0; j < 4; ++j) {
        float m3 = fminf(fminf(acc[rt][0][j], acc[rt][1][j]), acc[rt][2][j]);
        rmin[rt][j] = fminf(rmin[rt][j], m3);
      }

    __syncthreads();   // drains this iter's stage; next buf ready
  }

  // cross-lane min within each 16-lane col group (C/D: col=l&15, row=(l>>4)*4+j)
  #pragma unroll
  for (int rt = 0; rt < 3; ++rt)
    #pragma unroll
    for (int j = 0; j < 4; ++j) {
      float m = rmin[rt][j];
      m = fminf(m, __shfl_xor(m, 1, 64));
      m = fminf(m, __shfl_xor(m, 2, 64));
      m = fminf(m, __shfl_xor(m, 4, 64));
      m = fminf(m, __shfl_xor(m, 8, 64));
      if (l15 == 0) sred[w][rt * 16 + l4 * 4 + j] = m;
    }
  __syncthreads();
  int tt = threadIdx.x;
  if (tt < 96) {
    int h = tt / 48, r = tt - (tt / 48) * 48;
    float m = fminf(sred[h * 2][r], sred[h * 2 + 1][r]);  // combine col-halves
    rminw[(size_t)ns * NP + brow + h * 48 + r] = m;
  }
}

// ---------------- reduce: min over segments + qn, partial sums ------------
__global__ __launch_bounds__(64) void rowmin_kernel(
    const float* __restrict__ rminw, const float* __restrict__ qn,
    float* __restrict__ partial) {
  int r = blockIdx.x * 64 + threadIdx.x;   // grid 225 -> covers 14400
  float m = INFINITY;
  #pragma unroll
  for (int s = 0; s < NS; ++s) m = fminf(m, rminw[(size_t)s * NP + r]);
  float val = m + qn[r];
  #pragma unroll
  for (int off = 32; off; off >>= 1) val += __shfl_down(val, off, 64);
  if (threadIdx.x == 0) partial[blockIdx.x] = val;
}

__global__ __launch_bounds__(256) void final_kernel(
    const float* __restrict__ partial, float* __restrict__ out) {
  int t = threadIdx.x;
  float v = (t < 225) ? partial[t] : 0.f;
  #pragma unroll
  for (int off = 32; off; off >>= 1) v += __shfl_down(v, off, 64);
  __shared__ float s[4];
  if ((t & 63) == 0) s[t >> 6] = v;
  __syncthreads();
  if (t == 0) out[0] = s[0] + s[1] + s[2] + s[3];
}

extern "C" void kernel_launch(void* const* d_in, const int* in_sizes, int n_in,
                              void* d_out, int out_size, void* d_ws, size_t ws_size,
                              hipStream_t stream) {
  const float* resv = (const float*)d_in[0];
  const float* valv = (const float*)d_in[1];
  char* ws = (char*)d_ws;
  ushort_t* Qb   = (ushort_t*)ws;                 // 2,764,800 B
  ushort_t* Kb   = (ushort_t*)(ws + 2764800);     // 2,764,800 B
  float* qn      = (float*)(ws + 5529600);        //    57,600 B
  float* rminw   = (float*)(ws + 5587200);        //   345,600 B
  float* partial = (float*)(ws + 5932800);        //       900 B
  float* out = (float*)d_out;

  prep_kernel<<<7200, 256, 0, stream>>>(resv, valv, Qb, Kb, qn);
  knn_kernel<<<900, 256, 0, stream>>>(Qb, Kb, rminw);
  rowmin_kernel<<<225, 64, 0, stream>>>(rminw, qn, partial);
  final_kernel<<<1, 256, 0, stream>>>(partial, out);
}